// Round 11
// baseline (774.607 us; speedup 1.0000x reference)
//
#include <hip/hip_runtime.h>
#include <cstdint>
#include <cstddef>

// Problem constants
#define T_TOKN 16
#define NUNITS 4096
#define LPATH  32
#define NPATHS 1024
#define BNUM   8

typedef __attribute__((ext_vector_type(8))) short short8;   // 8 bf16 in 4 VGPRs
typedef __attribute__((ext_vector_type(4))) float f32x4;    // MFMA accumulator

// ws float offsets (identical to round 6, which passed)
enum : size_t {
  OFF_WFRAG   = 0,                        // 524288 ushort: lstm W frags [tf|tb|pf|pb]
  OFF_LINFRAG = 262144,                   // 65536 ushort: lin/ul B-frags
  OFF_OUTF    = 294912,                   // token fwd h, bf16 16x4096x128
  OFF_OUTB    = OFF_OUTF + 4194304,       // token bwd h (time-realigned), bf16
  OFF_OUTLIN  = OFF_OUTB + 4194304,       // f32 16x4096x128
  OFF_SCORES  = OFF_OUTLIN + 8388608,     // f32 16x4096
  OFF_TOKFEAT = OFF_SCORES + 65536,       // f32 4096x128
  OFF_POUTF   = OFF_TOKFEAT + 524288,     // path fwd h, bf16 32x1024x128
  OFF_POUTB   = OFF_POUTF + 2097152,
  OFF_INT     = OFF_POUTB + 2097152,      // ints: tok_len 4096 | fe 1024 | p_len 1024 | off_p 1024 | un_p 1024
  WS_FLOATS   = OFF_INT + 8192
};

static __device__ __forceinline__ unsigned short f2bf(float f) {
  union { float f; unsigned u; } v; v.f = f;
  unsigned r = v.u + 0x7fffu + ((v.u >> 16) & 1u);
  return (unsigned short)(r >> 16);
}
static __device__ __forceinline__ unsigned pack_bf(float a, float b) {
  return (unsigned)f2bf(a) | ((unsigned)f2bf(b) << 16);
}
static __device__ __forceinline__ float sigf(float x)      { return 1.f / (1.f + __expf(-x)); }
static __device__ __forceinline__ float tanhfast(float x)  { return 2.f / (1.f + __expf(-2.f * x)) - 1.f; }

// ---------------------------------------------------------------------------
// prep (round-6 verbatim): (a) lstm W frags: element (mat, wv8, ks, ct, lane, i)
// = Wc[g][k], g = wv8*64 + ct*16 + (lane&15), k = ks*32 + (lane>>4)*8 + i,
// Wc = [Wi | Wh].  (b) lin/ul B-frags.  (c) lengths / path metadata.
// ---------------------------------------------------------------------------
__global__ void prep_kernel(
    const float* __restrict__ tWif, const float* __restrict__ tWhf,
    const float* __restrict__ tWib, const float* __restrict__ tWhb,
    const float* __restrict__ pWif, const float* __restrict__ pWhf,
    const float* __restrict__ pWib, const float* __restrict__ pWhb,
    const float* __restrict__ linW, const float* __restrict__ ulW,
    const int* __restrict__ units, const int* __restrict__ paths,
    const int* __restrict__ upd, const int* __restrict__ ppd,
    float* __restrict__ ws, int* __restrict__ ip)
{
  int idx = blockIdx.x * 256 + threadIdx.x;
  if (idx < 524288) {
    unsigned short* wf = (unsigned short*)(ws + OFF_WFRAG);
    int mat = idx >> 17, rem = idx & 131071;
    int i  = rem & 7;
    int lane = (rem >> 3) & 63;
    int ct = (rem >> 9) & 3;
    int ks = (rem >> 11) & 7;
    int wv = (rem >> 14) & 7;
    int g = wv * 64 + ct * 16 + (lane & 15);
    int k = ks * 32 + ((lane >> 4) << 3) + i;
    const float* Wi; const float* Wh;
    switch (mat) {
      case 0: Wi = tWif; Wh = tWhf; break;
      case 1: Wi = tWib; Wh = tWhb; break;
      case 2: Wi = pWif; Wh = pWhf; break;
      default: Wi = pWib; Wh = pWhb; break;
    }
    float v = (k < 128) ? Wi[g * 128 + k] : Wh[g * 128 + (k - 128)];
    wf[idx] = f2bf(v);
  } else if (idx < 524288 + 65536) {
    unsigned short* lf = (unsigned short*)(ws + OFF_LINFRAG);
    int i2 = idx - 524288;
    int mat = i2 >> 15, rem = i2 & 32767;
    int i  = rem & 7;
    int lane = (rem >> 3) & 63;
    int ks = (rem >> 9) & 7;
    int ct = (rem >> 12) & 7;
    int e = ct * 16 + (lane & 15);
    int k = ks * 32 + ((lane >> 4) << 3) + i;
    const float* W = mat ? ulW : linW;
    lf[i2] = f2bf(W[e * 256 + k]);
  } else if (idx < 589824 + 4096) {
    int n = idx - 589824;
    int len = T_TOKN;
    for (int t = 0; t < T_TOKN; ++t)
      if (units[t * NUNITS + n] == 0) { len = t; break; }
    ip[n] = len;                                   // tok_len
  } else if (idx < 589824 + 5120) {
    int p = idx - (589824 + 4096);
    int* fe_a  = ip + 4096;
    int* p_len = ip + 5120;
    int* off_p = ip + 6144;
    int* un_p  = ip + 7168;
    int cum = 0; int d = BNUM - 1;
    for (int dd = 0; dd < BNUM; ++dd) {
      int c2 = cum + ppd[dd];
      if (p < c2) { d = dd; break; }
      cum = c2;
    }
    int off = 0;
    for (int dd = 0; dd < d; ++dd) off += upd[dd];
    int un = upd[d];
    off_p[p] = off; un_p[p] = un;
    int f = LPATH;
    for (int t = 0; t < LPATH; ++t)
      if (paths[t * NPATHS + p] == -1) { f = t; break; }
    fe_a[p] = f;
    int pl = LPATH;
    for (int t = 0; t < LPATH; ++t) {
      int v = paths[t * NPATHS + p];
      if ((t >= f) || (v < 0) || (v > un)) { pl = t; break; }
    }
    p_len[p] = pl;
  }
}

// ---------------------------------------------------------------------------
// MFMA BiLSTM — round-6 structure (fused K=256, 16 waves, 2 barriers/step,
// x(t+1) register prefetch) with HALVED tile: MR=16 rows -> LDS 41.3 KB ->
// TWO co-resident blocks/CU (r6's 83 KB forced 1 block/CU = zero overlap,
// its diagnosed limit).  Grid doubles; __launch_bounds__(1024,8) pins
// VGPR<=64 so 2x16 waves fit.  Wave wv owns 32 gate-cols (B resident,
// 32 VGPR).  MODE 0: token, M=16 units, wave==unit in pointwise.
// MODE 1: path, M=4 paths (tile rows 4-15 stay zero; guards on ug<M).
// ---------------------------------------------------------------------------
template <int MODE>
__global__ __launch_bounds__(1024, 8) void lstm_kernel(
    const unsigned short* __restrict__ wfragAll,
    const float* __restrict__ biasF, const float* __restrict__ biasB,
    const float* __restrict__ src,       // emb or tok_feat (f32)
    const int* __restrict__ idxsrc,      // units or paths
    const int* __restrict__ lens,        // tok_len or p_len
    const int* __restrict__ fe_a, const int* __restrict__ off_p, const int* __restrict__ un_p,
    unsigned short* __restrict__ outF, unsigned short* __restrict__ outB)
{
  constexpr int NN   = MODE ? NPATHS : NUNITS;
  constexpr int TT   = MODE ? LPATH : T_TOKN;
  constexpr int M    = MODE ? 4 : 16;     // real sequences per block
  constexpr int ASTR = 264;               // A-tile row stride (ushorts)
  constexpr int GSTR = 514;               // gates row stride (f32)

  __shared__ unsigned short ash[16 * ASTR];  // [u][0:128)=x  [u][128:256)=h
  __shared__ float gates[16 * GSTR];

  int tid  = threadIdx.x;
  int dir  = blockIdx.y;
  int n0   = blockIdx.x * M;
  int lane = tid & 63, wv = tid >> 6;       // wv in [0,16)

  // ---- resident B fragments: wave wv covers gates [wv*32, wv*32+32) ----
  const unsigned short* wbase =
      wfragAll + (size_t)((MODE ? 2 : 0) + dir) * 131072;
  int wv8 = wv >> 1;
  short8 bfr[8][2];
#pragma unroll
  for (int ks = 0; ks < 8; ++ks)
#pragma unroll
    for (int c2 = 0; c2 < 2; ++c2) {
      int ct = ((wv & 1) << 1) | c2;
      bfr[ks][c2] = *(const short8*)&wbase[((((wv8 * 8 + ks) * 4 + ct) * 64) + lane) * 8];
    }

  // ---- zero LDS (h region; MODE 1: whole tile incl dummy rows) ----
  if (MODE == 0) {
    for (int i = tid; i < 16 * 128; i += 1024)
      ash[(i >> 7) * ASTR + 128 + (i & 127)] = 0;
  } else {
    for (int i = tid; i < 16 * ASTR; i += 1024) ash[i] = 0;
  }

  // ---- unified gather/pointwise thread map ----
  // MODE 0: ug = tid>>6 == wv (unit), j2 = even j pair.  MODE 1: ug = tid>>7
  // (path, only <M real), j2 = scalar j.
  const float* bcp = dir ? biasB : biasF;
  int j2 = MODE ? (tid & 127) : ((tid & 63) * 2);
  int ug = MODE ? (tid >> 7)  : (tid >> 6);
  bool pact = (MODE == 0) || (ug < M);
  int un_ = n0 + (MODE ? min(ug, M - 1) : ug);   // clamped for safe loads
  float2 b2[4];
#pragma unroll
  for (int q = 0; q < 4; ++q) {
    if (MODE == 0) b2[q] = *(const float2*)&bcp[q * 128 + j2];
    else           b2[q] = make_float2(bcp[q * 128 + j2], 0.f);
  }
  float cstA = 0.f, cstB = 0.f;
  int ulen = lens[un_];
  int gfe = 0, goff = 0, gun = 0;
  if (MODE) { gfe = fe_a[un_]; goff = off_p[un_]; gun = un_p[un_]; }

  // ---- preamble: load x(0) into regs ----
  float2 xq; float xs = 0.f;
  if (MODE == 0) {
    int tau = dir ? min(max(ulen - 1, 0), TT - 1) : 0;
    int tok = idxsrc[tau * NN + un_];
    xq = *(const float2*)&src[(size_t)tok * 128 + j2];
  } else {
    int tau = dir ? min(max(ulen - 1, 0), TT - 1) : 0;
    int v = idxsrc[tau * NN + un_];
    if ((tau < gfe) && (v >= 0) && (v < gun))
      xs = src[(size_t)min(v + goff, NUNITS - 1) * 128 + j2];
  }
  __syncthreads();   // LDS init complete before first x write (r4 race fix)

  for (int t = 0; t < TT; ++t) {
    // ---- write x(t) from prefetch regs ----
    if (MODE == 0) {
      *(unsigned*)&ash[ug * ASTR + j2] = pack_bf(xq.x, xq.y);
    } else if (ug < M) {
      ash[ug * ASTR + j2] = f2bf(xs);
    }
    __syncthreads();   // A-tile complete: x(t) + h(t-1)

    // ---- MFMA gate GEMM (K=256, resident B) + next-step prefetch ----
    {
      int tn = (t + 1 < TT) ? t + 1 : t;
      int taun = dir ? min(max(ulen - 1 - tn, 0), TT - 1) : tn;
      int vn = idxsrc[taun * NN + un_];   // issued early; overlaps MFMA
      f32x4 acc[2];
#pragma unroll
      for (int c2 = 0; c2 < 2; ++c2) {
        f32x4 z = {0.f, 0.f, 0.f, 0.f};
        acc[c2] = z;
      }
#pragma unroll
      for (int ks = 0; ks < 8; ++ks) {
        short8 af = *(const short8*)&ash[(lane & 15) * ASTR + ks * 32 + ((lane >> 4) << 3)];
#pragma unroll
        for (int c2 = 0; c2 < 2; ++c2)
          acc[c2] = __builtin_amdgcn_mfma_f32_16x16x32_bf16(
              af, bfr[ks][c2], acc[c2], 0, 0, 0);
      }
      // dependent x(t+1) load — latency overlaps gates-write + barrier
      if (MODE == 0) {
        xq = *(const float2*)&src[(size_t)vn * 128 + j2];
      } else {
        bool keep = (taun < gfe) && (vn >= 0) && (vn < gun);
        xs = 0.f;
        if (keep) xs = src[(size_t)min(vn + goff, NUNITS - 1) * 128 + j2];
      }
      // ---- preacts -> LDS gates (C-layout: col=lane&15, row=quad*4+r) ----
#pragma unroll
      for (int c2 = 0; c2 < 2; ++c2) {
        int g = wv * 32 + c2 * 16 + (lane & 15);
#pragma unroll
        for (int r = 0; r < 4; ++r) {
          int u = ((lane >> 4) << 2) + r;
          gates[u * GSTR + g] = acc[c2][r];
        }
      }
    }
    __syncthreads();   // gates ready; all A-tile reads done

    // ---- pointwise LSTM update ----
    if (MODE == 0) {
      int u = ug, n = n0 + ug;
      float2 g0 = *(const float2*)&gates[u * GSTR + j2];
      float2 g1 = *(const float2*)&gates[u * GSTR + 128 + j2];
      float2 g2 = *(const float2*)&gates[u * GSTR + 256 + j2];
      float2 g3 = *(const float2*)&gates[u * GSTR + 384 + j2];
      float i0 = sigf(g0.x + b2[0].x), i1 = sigf(g0.y + b2[0].y);
      float f0 = sigf(g1.x + b2[1].x), f1 = sigf(g1.y + b2[1].y);
      float c0 = tanhfast(g2.x + b2[2].x), c1 = tanhfast(g2.y + b2[2].y);
      float o0 = sigf(g3.x + b2[3].x), o1 = sigf(g3.y + b2[3].y);
      float cA = f0 * cstA + i0 * c0;
      float cB = f1 * cstB + i1 * c1;
      cstA = cA; cstB = cB;
      float h0 = o0 * tanhfast(cA);
      float h1 = o1 * tanhfast(cB);
      unsigned hp = pack_bf(h0, h1);
      *(unsigned*)&ash[u * ASTR + 128 + j2] = hp;
      if (dir == 0) {
        *(unsigned*)&outF[((size_t)t * NN + n) * 128 + j2] = hp;
      } else {
        int L = ulen;
        if (t < L) *(unsigned*)&outB[((size_t)(L - 1 - t) * NN + n) * 128 + j2] = hp;
        else       *(unsigned*)&outB[((size_t)t * NN + n) * 128 + j2] = 0;
      }
    } else if (pact) {
      int u = ug, n = n0 + ug;
      float p0 = gates[u * GSTR + j2]       + b2[0].x;
      float p1 = gates[u * GSTR + 128 + j2] + b2[1].x;
      float p2 = gates[u * GSTR + 256 + j2] + b2[2].x;
      float p3 = gates[u * GSTR + 384 + j2] + b2[3].x;
      float ig = sigf(p0), fg = sigf(p1), gg = tanhfast(p2), og = sigf(p3);
      float c = fg * cstA + ig * gg;
      cstA = c;
      float h = og * tanhfast(c);
      unsigned short hb = f2bf(h);
      ash[u * ASTR + 128 + j2] = hb;
      if (dir == 0) {
        outF[((size_t)t * NN + n) * 128 + j2] = hb;
      } else {
        int L = ulen;
        if (t < L) outB[((size_t)(L - 1 - t) * NN + n) * 128 + j2] = hb;
        else       outB[((size_t)t * NN + n) * 128 + j2] = 0;
      }
    }
    // next-iter x write touches only x region (disjoint from h/gates) -> safe
  }
}

// ---------------------------------------------------------------------------
// MFMA GEMM (round-6 verbatim): rows x 128, K=256, A = bf16 [INf|INb] from
// global, B resident.  EPI 0: row-validity mask, f32 store.  EPI 1: + fused
// LayerNorm + tanh + attention scores.
// ---------------------------------------------------------------------------
template <int EPI>
__global__ __launch_bounds__(256) void gemm_mfma(
    const unsigned short* __restrict__ INf, const unsigned short* __restrict__ INb,
    const int* __restrict__ lens,
    const unsigned short* __restrict__ Bfrag, const float* __restrict__ bias,
    float* __restrict__ OUT, float* __restrict__ scores,
    const float* __restrict__ lng, const float* __restrict__ lnb,
    const float* __restrict__ attw, const float* __restrict__ attb,
    const int* __restrict__ units, int Nn)
{
  constexpr int OSTR = 132;
  __shared__ float outs[64 * OSTR];
  __shared__ float red1[256];
  __shared__ float red2[256];
  __shared__ float rowm[64], rowr[64];
  __shared__ float awsh[128], lgsh[128], lbsh[128];

  int tid = threadIdx.x, lane = tid & 63, wv = tid >> 6;
  int row0 = blockIdx.x * 64;
  int t = row0 / Nn, n0 = row0 % Nn;

  if (EPI == 1 && tid < 128) {
    awsh[tid] = attw[tid]; lgsh[tid] = lng[tid]; lbsh[tid] = lnb[tid];
  }

  short8 bfr[8][2];
#pragma unroll
  for (int ks = 0; ks < 8; ++ks)
#pragma unroll
    for (int c2 = 0; c2 < 2; ++c2) {
      int ct = wv * 2 + c2;
      bfr[ks][c2] = *(const short8*)&Bfrag[(((ct * 8 + ks) * 64) + lane) * 8];
    }

  int rb = lane & 15;
  int koq = (lane >> 4) << 3;
  bool val[4];
#pragma unroll
  for (int rt = 0; rt < 4; ++rt)
    val[rt] = (EPI == 1) ? true : (t < lens[n0 + rt * 16 + rb]);

  f32x4 acc[4][2];
#pragma unroll
  for (int rt = 0; rt < 4; ++rt)
#pragma unroll
    for (int c2 = 0; c2 < 2; ++c2) {
      f32x4 z = {0.f, 0.f, 0.f, 0.f};
      acc[rt][c2] = z;
    }

#pragma unroll
  for (int ks = 0; ks < 8; ++ks) {
    const unsigned short* P = (ks < 4) ? INf : INb;
    int koff = (ks & 3) * 32 + koq;
#pragma unroll
    for (int rt = 0; rt < 4; ++rt) {
      short8 a = {0, 0, 0, 0, 0, 0, 0, 0};
      if (val[rt])
        a = *(const short8*)&P[((size_t)(row0 + rt * 16 + rb)) * 128 + koff];
#pragma unroll
      for (int c2 = 0; c2 < 2; ++c2)
        acc[rt][c2] = __builtin_amdgcn_mfma_f32_16x16x32_bf16(
            a, bfr[ks][c2], acc[rt][c2], 0, 0, 0);
    }
  }

  float bc[2];
#pragma unroll
  for (int c2 = 0; c2 < 2; ++c2) bc[c2] = bias[wv * 32 + c2 * 16 + rb];
#pragma unroll
  for (int rt = 0; rt < 4; ++rt)
#pragma unroll
    for (int c2 = 0; c2 < 2; ++c2) {
      int col = wv * 32 + c2 * 16 + rb;
      int ub  = rt * 16 + ((lane >> 4) << 2);
#pragma unroll
      for (int r = 0; r < 4; ++r)
        outs[(ub + r) * OSTR + col] = acc[rt][c2][r] + bc[c2];
    }
  __syncthreads();

  int row = tid >> 2, seg = tid & 3;
  const float* rp = &outs[row * OSTR + seg * 32];
  size_t go = ((size_t)(row0 + row)) * 128 + seg * 32;

  if (EPI == 0) {
#pragma unroll
    for (int x = 0; x < 8; ++x)
      *(f32x4*)&OUT[go + x * 4] = *(const f32x4*)&rp[x * 4];
  } else {
    f32x4 v[8];
    float s = 0.f, s2 = 0.f;
#pragma unroll
    for (int x = 0; x < 8; ++x) {
      v[x] = *(const f32x4*)&rp[x * 4];
#pragma unroll
      for (int c = 0; c < 4; ++c) { s += v[x][c]; s2 += v[x][c] * v[x][c]; }
    }
    red1[tid] = s; red2[tid] = s2;
    __syncthreads();
    if (tid < 64) {
      float a = red1[tid * 4] + red1[tid * 4 + 1] + red1[tid * 4 + 2] + red1[tid * 4 + 3];
      float b = red2[tid * 4] + red2[tid * 4 + 1] + red2[tid * 4 + 2] + red2[tid * 4 + 3];
      float m = a * (1.f / 128.f);
      float var = b * (1.f / 128.f) - m * m;
      rowm[tid] = m;
      rowr[tid] = rsqrtf(var + 1e-5f);
    }
    __syncthreads();
    float m = rowm[row], rs = rowr[row];
    float sp = 0.f;
#pragma unroll
    for (int x = 0; x < 8; ++x) {
#pragma unroll
      for (int c = 0; c < 4; ++c) {
        int col = seg * 32 + x * 4 + c;
        float q = tanhfast((v[x][c] - m) * rs * lgsh[col] + lbsh[col]);
        sp += q * awsh[col];
      }
      *(f32x4*)&OUT[go + x * 4] = v[x];
    }
    red1[tid] = sp;
    __syncthreads();
    if (tid < 64) {
      float s3 = red1[tid * 4] + red1[tid * 4 + 1] + red1[tid * 4 + 2] + red1[tid * 4 + 3]
               + attb[0];
      int n = n0 + tid;
      if (units[t * NUNITS + n] == 0) s3 = -1e9f;
      scores[t * NUNITS + n] = s3;
    }
  }
}

// ---------------------------------------------------------------------------
// Softmax over T=16 + attention-weighted pooling -> tok_feat[n][e]
// ---------------------------------------------------------------------------
__global__ __launch_bounds__(128) void softmax_feat_kernel(
    const float* __restrict__ scores, const float* __restrict__ out_lin,
    float* __restrict__ tok_feat)
{
  int n = blockIdx.x;
  int e = threadIdx.x;
  float s[T_TOKN];
  float m = -1e30f;
#pragma unroll
  for (int t = 0; t < T_TOKN; ++t) { s[t] = scores[t * NUNITS + n]; m = fmaxf(m, s[t]); }
  float sum = 0.f;
#pragma unroll
  for (int t = 0; t < T_TOKN; ++t) { s[t] = expf(s[t] - m); sum += s[t]; }
  float inv = 1.f / sum;
  float a = 0.f;
#pragma unroll
  for (int t = 0; t < T_TOKN; ++t)
    a += s[t] * inv * out_lin[((size_t)t * NUNITS + n) * 128 + e];
  tok_feat[n * 128 + e] = a;
}

// ---------------------------------------------------------------------------
extern "C" void kernel_launch(void* const* d_in, const int* in_sizes, int n_in,
                              void* d_out, int out_size, void* d_ws, size_t ws_size,
                              hipStream_t stream)
{
  const int*   units = (const int*)d_in[0];
  const int*   paths = (const int*)d_in[1];
  const int*   upd   = (const int*)d_in[2];
  const int*   ppd   = (const int*)d_in[3];
  const float* emb   = (const float*)d_in[4];
  const float* tWif  = (const float*)d_in[5];
  const float* tWhf  = (const float*)d_in[6];
  const float* tbf   = (const float*)d_in[7];
  const float* tWib  = (const float*)d_in[8];
  const float* tWhb  = (const float*)d_in[9];
  const float* tbb   = (const float*)d_in[10];
  const float* linW  = (const float*)d_in[11];
  const float* linb  = (const float*)d_in[12];
  const float* lng   = (const float*)d_in[13];
  const float* lnb   = (const float*)d_in[14];
  const float* attw  = (const float*)d_in[15];
  const float* attb  = (const float*)d_in[16];
  const float* pWif  = (const float*)d_in[17];
  const float* pWhf  = (const float*)d_in[18];
  const float* pbf   = (const float*)d_in[19];
  const float* pWib  = (const float*)d_in[20];
  const float* pWhb  = (const float*)d_in[21];
  const float* pbb   = (const float*)d_in[22];
  const float* ulW   = (const float*)d_in[23];
  const float* ulb   = (const float*)d_in[24];

  float* ws = (float*)d_ws;
  int*   ip = (int*)(ws + OFF_INT);
  if (ws_size < WS_FLOATS * sizeof(float)) return;

  unsigned short* wfrag   = (unsigned short*)(ws + OFF_WFRAG);
  unsigned short* linfrag = (unsigned short*)(ws + OFF_LINFRAG);
  unsigned short* ulfrag  = linfrag + 32768;
  unsigned short* OUTF  = (unsigned short*)(ws + OFF_OUTF);
  unsigned short* OUTB  = (unsigned short*)(ws + OFF_OUTB);
  unsigned short* POUTF = (unsigned short*)(ws + OFF_POUTF);
  unsigned short* POUTB = (unsigned short*)(ws + OFF_POUTB);

  prep_kernel<<<2324, 256, 0, stream>>>(tWif, tWhf, tWib, tWhb,
                                        pWif, pWhf, pWib, pWhb,
                                        linW, ulW, units, paths, upd, ppd,
                                        ws, ip);

  lstm_kernel<0><<<dim3(NUNITS / 16, 2), 1024, 0, stream>>>(
      wfrag, tbf, tbb, emb, units, ip /*tok_len*/, nullptr, nullptr, nullptr,
      OUTF, OUTB);

  gemm_mfma<1><<<1024, 256, 0, stream>>>(
      OUTF, OUTB, ip /*tok_len*/, linfrag, linb,
      ws + OFF_OUTLIN, ws + OFF_SCORES, lng, lnb, attw, attb, units, NUNITS);

  softmax_feat_kernel<<<4096, 128, 0, stream>>>(ws + OFF_SCORES, ws + OFF_OUTLIN,
                                                ws + OFF_TOKFEAT);

  lstm_kernel<1><<<dim3(NPATHS / 4, 2), 1024, 0, stream>>>(
      wfrag, pbf, pbb, ws + OFF_TOKFEAT, paths, ip + 5120 /*p_len*/,
      ip + 4096 /*fe*/, ip + 6144 /*off_p*/, ip + 7168 /*un_p*/,
      POUTF, POUTB);

  gemm_mfma<0><<<512, 256, 0, stream>>>(
      POUTF, POUTB, ip + 5120 /*p_len*/, ulfrag, ulb,
      (float*)d_out, nullptr, nullptr, nullptr, nullptr, nullptr, nullptr, NPATHS);
}